// Round 6
// baseline (182.964 us; speedup 1.0000x reference)
//
#include <hip/hip_runtime.h>
#include <hip/hip_bf16.h>
#include <cstdint>

namespace {

typedef __bf16 bf8v __attribute__((ext_vector_type(8)));
typedef __bf16 bf4v __attribute__((ext_vector_type(4)));
typedef float  f4v  __attribute__((ext_vector_type(4)));

constexpr int kB = 128;   // batch
constexpr int kQ = 32;    // query len
constexpr int kD = 512;   // doc len
constexpr int kE = 300;   // embed dim
constexpr int kC = 128;   // conv channels
constexpr int kK = 11;    // RBF kernels

// workspace layout (bytes)
// wb:  [6 slabs][10 ks][128 c][32 e] bf16 = 491520 B (slabs: c1j0 | c2j0 c2j1 | c3j0 c3j1 c3j2)
// qnb: [3][B][32][128]  bf16   dnb: [3][B][512][128] bf16   pkq: [9][B][32][11] f32
constexpr size_t QNB_B = 491520;
constexpr size_t DNB_B = 3637248;
constexpr size_t PKQ_B = 53968896;

constexpr float LOG2E = 1.4426950408889634f;

constexpr int XS_STRIDE = 344;   // elems; 688 B row stride (2-way b128 aliasing = ~free)

// ---------------- weight repack to bf16 [slab][ks][c][32] ----------------
__global__ __launch_bounds__(256) void prep_kernel(
    const float* __restrict__ w1, const float* __restrict__ w2, const float* __restrict__ w3,
    __bf16* __restrict__ wb)
{
  int i = blockIdx.x * 256 + threadIdx.x;   // 0..245759
  if (i >= 245760) return;
  int el = i & 31;
  int sc = i >> 5;              // (slab*10 + ks)*128 + c
  int c  = sc & 127;
  int sk = sc >> 7;             // slab*10 + ks
  int slab = sk / 10;
  int ks = sk - slab * 10;
  int e = ks * 32 + el;
  float v = 0.f;
  if (e < kE) {
    if (slab == 0)      v = w1[c * kE + e];
    else if (slab <= 2) v = w2[(c * kE + e) * 2 + (slab - 1)];
    else                v = w3[(c * kE + e) * 3 + (slab - 3)];
  }
  wb[i] = (__bf16)v;
}

// ---------------- per-grp MFMA loop: depth-2 W prefetch (3 reg sets), depth-1 A ----------------
// step sg = j*10+ks (grp-local). W chunk address is LINEAR in sg: 4096 elems (8 KB) per step.
template<int NJ, int SLAB0>
__device__ __forceinline__ void conv_grp(
    const __bf16* __restrict__ wb, const __bf16* __restrict__ Xs,
    int lr, int g, int wm, int wn, f4v (&acc)[2][4])
{
  constexpr int N = NJ * 10;
  const __bf16* wl = wb + (size_t)SLAB0 * 10 * 4096 + (size_t)(wn * 64 + lr) * 32 + g * 8;
  const int arow = wm * 32 + lr;
  const int ae   = g * 8;

  bf8v W[3][4];
  bf8v A[2][2];
  // prologue: W chunks sg=0,1; A chunk sg=0
  #pragma unroll
  for (int nf = 0; nf < 4; ++nf) W[0][nf] = *(const bf8v*)(wl + nf * 512);
  #pragma unroll
  for (int nf = 0; nf < 4; ++nf) W[1][nf] = *(const bf8v*)(wl + 4096 + nf * 512);
  #pragma unroll
  for (int mf = 0; mf < 2; ++mf)
    A[0][mf] = *(const bf8v*)&Xs[(arow + mf * 16) * XS_STRIDE + ae];

  #pragma unroll
  for (int sg = 0; sg < N; ++sg) {
    const int cur = sg % 3, nxt = (sg + 2) % 3, ca = sg & 1;
    if (sg + 2 < N) {
      #pragma unroll
      for (int nf = 0; nf < 4; ++nf)
        W[nxt][nf] = *(const bf8v*)(wl + (size_t)(sg + 2) * 4096 + nf * 512);
    }
    if (sg + 1 < N) {
      const int j1 = (sg + 1) / 10, ks1 = (sg + 1) % 10;
      #pragma unroll
      for (int mf = 0; mf < 2; ++mf)
        A[ca ^ 1][mf] = *(const bf8v*)&Xs[(arow + j1 + mf * 16) * XS_STRIDE + ks1 * 32 + ae];
    }
    #pragma unroll
    for (int nf = 0; nf < 4; ++nf) {
      acc[0][nf] = __builtin_amdgcn_mfma_f32_16x16x32_bf16(A[ca][0], W[cur][nf], acc[0][nf], 0, 0, 0);
      acc[1][nf] = __builtin_amdgcn_mfma_f32_16x16x32_bf16(A[ca][1], W[cur][nf], acc[1][nf], 0, 0, 0);
    }
  }
}

// ---------------- fused conv (all 3 widths) + bias + relu + L2-norm -> bf16 [L][C] ----------------
// grid (9, B): x==0 -> query (L=32), x=1..8 -> doc tile (p0=(x-1)*64)
// 256 threads = 4 waves; tile 64 pos x 128 ch; wave (wm,wn) -> rows wm*32+, cols wn*64+
__global__ __launch_bounds__(256, 3) void conv_fused(
    const float* __restrict__ qe, const float* __restrict__ de,
    const __bf16* __restrict__ wb,
    const float* __restrict__ b1, const float* __restrict__ b2, const float* __restrict__ b3,
    __bf16* __restrict__ qnb, __bf16* __restrict__ dnb)
{
  const int bx = blockIdx.x;
  const int b  = blockIdx.y;
  const bool isq = (bx == 0);
  const int L  = isq ? kQ : kD;
  const int p0 = isq ? 0 : (bx - 1) * 64;
  const float* xsrc = (isq ? qe : de) + (size_t)b * L * kE;

  const int t = threadIdx.x;
  const int w = t >> 6, l = t & 63;
  const int wm = w & 1, wn = w >> 1;
  const int lr = l & 15, g = l >> 4;

  __shared__ __align__(16) __bf16 Xs[66 * XS_STRIDE];
  __shared__ float sqs[2][64];

  // stage x rows p0..p0+65, e 0..327 (zero-pad) as bf16
  for (int idx = t; idx < 66 * 82; idx += 256) {
    int row = idx / 82, c4 = idx - row * 82;
    int gp = p0 + row;
    float4 v = make_float4(0.f, 0.f, 0.f, 0.f);
    if (gp < L && c4 < 75) v = *(const float4*)(xsrc + (size_t)gp * kE + c4 * 4);
    bf4v hv = { (__bf16)v.x, (__bf16)v.y, (__bf16)v.z, (__bf16)v.w };
    *(bf4v*)&Xs[row * XS_STRIDE + c4 * 4] = hv;
  }
  __syncthreads();

  #pragma unroll
  for (int grp = 0; grp < 3; ++grp) {
    f4v acc[2][4];
    #pragma unroll
    for (int mf = 0; mf < 2; ++mf)
      #pragma unroll
      for (int nf = 0; nf < 4; ++nf)
        acc[mf][nf] = (f4v)0.f;

    if (grp == 0)      conv_grp<1, 0>(wb, Xs, lr, g, wm, wn, acc);
    else if (grp == 1) conv_grp<2, 1>(wb, Xs, lr, g, wm, wn, acc);
    else               conv_grp<3, 3>(wb, Xs, lr, g, wm, wn, acc);

    // epilogue: bias + relu + L2 norm over 128 channels
    const float* bias = (grp == 0) ? b1 : ((grp == 1) ? b2 : b3);
    float bvs[4];
    #pragma unroll
    for (int nf = 0; nf < 4; ++nf) bvs[nf] = bias[wn * 64 + nf * 16 + lr];

    f4v ssum[2];
    #pragma unroll
    for (int mf = 0; mf < 2; ++mf) {
      ssum[mf] = (f4v)0.f;
      #pragma unroll
      for (int nf = 0; nf < 4; ++nf)
        #pragma unroll
        for (int r = 0; r < 4; ++r) {
          float y = fmaxf(acc[mf][nf][r] + bvs[nf], 0.f);
          acc[mf][nf][r] = y;
          ssum[mf][r] += y * y;
        }
    }
    #pragma unroll
    for (int off = 1; off < 16; off <<= 1)
      #pragma unroll
      for (int mf = 0; mf < 2; ++mf)
        #pragma unroll
        for (int r = 0; r < 4; ++r)
          ssum[mf][r] += __shfl_xor(ssum[mf][r], off);

    __syncthreads();
    if (lr == 0) {
      #pragma unroll
      for (int mf = 0; mf < 2; ++mf)
        *(float4*)&sqs[wn][wm * 32 + mf * 16 + g * 4] = *(float4*)&ssum[mf];
    }
    __syncthreads();
    f4v inv[2];
    #pragma unroll
    for (int mf = 0; mf < 2; ++mf) {
      float4 o = *(const float4*)&sqs[1 - wn][wm * 32 + mf * 16 + g * 4];
      inv[mf][0] = 1.f / (sqrtf(ssum[mf][0] + o.x) + 1e-13f);
      inv[mf][1] = 1.f / (sqrtf(ssum[mf][1] + o.y) + 1e-13f);
      inv[mf][2] = 1.f / (sqrtf(ssum[mf][2] + o.z) + 1e-13f);
      inv[mf][3] = 1.f / (sqrtf(ssum[mf][3] + o.w) + 1e-13f);
    }
    // store bf16 [B][L][C]
    __bf16* outp = (isq ? qnb : dnb) + ((size_t)(grp * kB + b)) * L * kC;
    #pragma unroll
    for (int mf = 0; mf < 2; ++mf) {
      #pragma unroll
      for (int r = 0; r < 4; ++r) {
        int gp = p0 + wm * 32 + mf * 16 + g * 4 + r;
        if (gp < L) {
          #pragma unroll
          for (int nf = 0; nf < 4; ++nf) {
            int c = wn * 64 + nf * 16 + lr;
            outp[(size_t)gp * kC + c] = (__bf16)(acc[mf][nf][r] * inv[mf][r]);
          }
        }
      }
    }
  }
}

// ---------------- MFMA cosine + RBF pooling ----------------
// grid (9, B), 256 threads = 4 waves. Per block: S[512 d][32 q] for one (pair,b).
__global__ __launch_bounds__(256) void pool_mfma(
    const __bf16* __restrict__ qnb,  // [3][B][32][128]
    const __bf16* __restrict__ dnb,  // [3][B][512][128]
    const float* __restrict__ qmask, // [B][32]
    const float* __restrict__ dmask, // [B][512]
    float* __restrict__ pkq)         // [9][B][32][11]
{
  const int pair = blockIdx.x;
  const int b = blockIdx.y;
  const int qi = pair / 3, dj = pair - qi * 3;
  const __bf16* qb = qnb + ((size_t)qi * kB + b) * kQ * kC;
  const __bf16* db = dnb + ((size_t)dj * kB + b) * kD * kC;

  const int t = threadIdx.x;
  const int w = t >> 6, l = t & 63;
  const int lr = l & 15, g = l >> 4;

  __shared__ float red[4][2][16][kK];

  bf8v Bq[2][4];
  #pragma unroll
  for (int qt = 0; qt < 2; ++qt)
    #pragma unroll
    for (int kc = 0; kc < 4; ++kc)
      Bq[qt][kc] = *(const bf8v*)&qb[(size_t)(qt * 16 + lr) * kC + kc * 32 + g * 8];

  float qmv[2];
  #pragma unroll
  for (int qt = 0; qt < 2; ++qt) qmv[qt] = qmask[b * kQ + qt * 16 + lr];

  const float c1[10] = { 129.84255368f, 100.98865286f,  72.13475204f,  43.28085123f,  14.42695041f,
                         -14.42695041f, -43.28085123f, -72.13475204f, -100.98865286f, -129.84255368f };
  const float c2[10] = { -58.42914915f, -35.34602850f, -18.03368801f, -6.49212768f, -0.72134752f,
                          -0.72134752f,  -6.49212768f, -18.03368801f, -35.34602850f, -58.42914915f };
  const float C50 = -50.f * LOG2E;
  const float C0  = -500000.f * LOG2E;

  float pk[2][kK];
  #pragma unroll
  for (int qt = 0; qt < 2; ++qt)
    #pragma unroll
    for (int k = 0; k < kK; ++k) pk[qt][k] = 0.f;

  const int dt0 = w * 8;
  bf8v An[4];
  #pragma unroll
  for (int kc = 0; kc < 4; ++kc)
    An[kc] = *(const bf8v*)&db[(size_t)(dt0 * 16 + lr) * kC + kc * 32 + g * 8];

  for (int dtl = 0; dtl < 8; ++dtl) {
    const int drow0 = (dt0 + dtl) * 16;
    bf8v Ac[4];
    #pragma unroll
    for (int kc = 0; kc < 4; ++kc) Ac[kc] = An[kc];
    if (dtl < 7) {
      #pragma unroll
      for (int kc = 0; kc < 4; ++kc)
        An[kc] = *(const bf8v*)&db[(size_t)(drow0 + 16 + lr) * kC + kc * 32 + g * 8];
    }
    f4v acc0 = (f4v)0.f, acc1 = (f4v)0.f;
    #pragma unroll
    for (int kc = 0; kc < 4; ++kc) {
      acc0 = __builtin_amdgcn_mfma_f32_16x16x32_bf16(Ac[kc], Bq[0][kc], acc0, 0, 0, 0);
      acc1 = __builtin_amdgcn_mfma_f32_16x16x32_bf16(Ac[kc], Bq[1][kc], acc1, 0, 0, 0);
    }
    float4 dmv = *(const float4*)&dmask[b * kD + drow0 + g * 4];
    #pragma unroll
    for (int qt = 0; qt < 2; ++qt) {
      const f4v& a = qt ? acc1 : acc0;
      #pragma unroll
      for (int r = 0; r < 4; ++r) {
        float dm = (r == 0) ? dmv.x : (r == 1) ? dmv.y : (r == 2) ? dmv.z : dmv.w;
        float off = fmaf(dm, 1000.f, -1000.f);
        float s = a[r] * qmv[qt] * dm;
        float s2 = s * s;
        float base = fmaf(s2, C50, off);
        float dd = s - 1.f;
        pk[qt][0] += exp2f(fmaf(dd * dd, C0, off));
        #pragma unroll
        for (int k = 0; k < 10; ++k)
          pk[qt][k + 1] += exp2f(fmaf(c1[k], s, base) + c2[k]);
      }
    }
  }

  #pragma unroll
  for (int off = 16; off < 64; off <<= 1)
    #pragma unroll
    for (int qt = 0; qt < 2; ++qt)
      #pragma unroll
      for (int k = 0; k < kK; ++k)
        pk[qt][k] += __shfl_xor(pk[qt][k], off);

  if (l < 16) {
    #pragma unroll
    for (int qt = 0; qt < 2; ++qt)
      #pragma unroll
      for (int k = 0; k < kK; ++k)
        red[w][qt][lr][k] = pk[qt][k];
  }
  __syncthreads();
  for (int i = t; i < 2 * 16 * kK; i += 256) {
    int qt = i / (16 * kK);
    int rem = i - qt * 16 * kK;
    int lq = rem / kK, k = rem - lq * kK;
    float v = red[0][qt][lq][k] + red[1][qt][lq][k] + red[2][qt][lq][k] + red[3][qt][lq][k];
    int q = qt * 16 + lq;
    pkq[(((size_t)pair * kB + b) * kQ + q) * kK + k] = v * qmask[b * kQ + q];
  }
}

// ---------------- log-pool + dense layers ----------------
__global__ __launch_bounds__(128) void finalize_kernel(
    const float* __restrict__ pkq, const float* __restrict__ qmask,
    const float* __restrict__ dmask, const float* __restrict__ nsp,
    const float* __restrict__ dw, const float* __restrict__ dbp,
    const float* __restrict__ dmw, const float* __restrict__ dmbp,
    const float* __restrict__ dcw, float* __restrict__ out)
{
  const int b = blockIdx.x;
  const int t = threadIdx.x;
  __shared__ float sh[4];
  float dl = 0.f;
  for (int d = t; d < kD; d += 128) dl += dmask[b * kD + d];
  #pragma unroll
  for (int off = 1; off < 64; off <<= 1) dl += __shfl_xor(dl, off);
  if ((t & 63) == 0) sh[t >> 6] = dl;
  __syncthreads();
  const float idl = 1.f / (sh[0] + sh[1]);
  const float sc = nsp[0];
  float ps = 0.f, pm = 0.f;
  for (int i = t; i < 99; i += 128) {
    int pr = i / kK, kk = i - pr * kK;
    const float* base = pkq + ((size_t)pr * kB + b) * kQ * kK + kk;
    float ss = 0.f, sm = 0.f;
    for (int q = 0; q < kQ; ++q) {
      float v = base[q * kK];
      float qq = qmask[b * kQ + q];
      ss += __logf(fmaxf(v, 1e-10f)) * qq;
      sm += __logf(fmaxf(v * idl, 1e-10f)) * qq;
    }
    ps += dw[i] * ss;
    pm += dmw[i] * sm;
  }
  ps *= sc; pm *= sc;
  #pragma unroll
  for (int off = 1; off < 64; off <<= 1) { ps += __shfl_xor(ps, off); pm += __shfl_xor(pm, off); }
  __syncthreads();
  if ((t & 63) == 0) { sh[t >> 6] = ps; sh[2 + (t >> 6)] = pm; }
  __syncthreads();
  if (t == 0) {
    float PS = sh[0] + sh[1] + dbp[0];
    float PM = sh[2] + sh[3] + dmbp[0];
    out[b] = dcw[0] * PS + dcw[1] * PM;
  }
}

} // namespace

extern "C" void kernel_launch(void* const* d_in, const int* in_sizes, int n_in,
                              void* d_out, int out_size, void* d_ws, size_t ws_size,
                              hipStream_t stream) {
  const float* qe  = (const float*)d_in[0];
  const float* de  = (const float*)d_in[1];
  const float* qm  = (const float*)d_in[2];
  const float* dm  = (const float*)d_in[3];
  const float* w1  = (const float*)d_in[4];
  const float* b1  = (const float*)d_in[5];
  const float* w2  = (const float*)d_in[6];
  const float* b2  = (const float*)d_in[7];
  const float* w3  = (const float*)d_in[8];
  const float* b3  = (const float*)d_in[9];
  const float* ns  = (const float*)d_in[10];
  const float* dw  = (const float*)d_in[11];
  const float* db  = (const float*)d_in[12];
  const float* dmw = (const float*)d_in[13];
  const float* dmb = (const float*)d_in[14];
  const float* dcw = (const float*)d_in[15];
  float* out = (float*)d_out;

  char* wsb = (char*)d_ws;
  __bf16* wb  = (__bf16*)wsb;
  __bf16* qnb = (__bf16*)(wsb + QNB_B);
  __bf16* dnb = (__bf16*)(wsb + DNB_B);
  float*  pkq = (float*)(wsb + PKQ_B);

  prep_kernel<<<960, 256, 0, stream>>>(w1, w2, w3, wb);
  conv_fused<<<dim3(9, kB), 256, 0, stream>>>(qe, de, wb, b1, b2, b3, qnb, dnb);
  pool_mfma<<<dim3(9, kB), 256, 0, stream>>>(qnb, dnb, qm, dm, pkq);
  finalize_kernel<<<kB, 128, 0, stream>>>(pkq, qm, dm, ns, dw, db, dmw, dmb, dcw, out);
}

// Round 7
// 176.377 us; speedup vs baseline: 1.0373x; 1.0373x over previous
//
#include <hip/hip_runtime.h>
#include <hip/hip_bf16.h>
#include <cstdint>

namespace {

typedef __bf16 bf8v __attribute__((ext_vector_type(8)));
typedef __bf16 bf4v __attribute__((ext_vector_type(4)));
typedef float  f4v  __attribute__((ext_vector_type(4)));

constexpr int kB = 128;   // batch
constexpr int kQ = 32;    // query len
constexpr int kD = 512;   // doc len
constexpr int kE = 300;   // embed dim
constexpr int kC = 128;   // conv channels
constexpr int kK = 11;    // RBF kernels

// workspace layout (bytes)
// wb:  [60 chunks][512 slots][8] bf16 = 491520 B, chunk = slab*10+ks,
//      slot s holds W granule (c = s>>2, g = (s&3) ^ ((c>>1)&3))  [read-swizzle baked in]
// qnb: [3][B][32][128]  bf16   dnb: [3][B][512][128] bf16   pkq: [9][B][32][11] f32
constexpr size_t QNB_B = 491520;
constexpr size_t DNB_B = 3637248;
constexpr size_t PKQ_B = 53968896;

constexpr float LOG2E = 1.4426950408889634f;

constexpr int XS_STRIDE = 336;   // elems; 672 B row stride -> 2-way banks on b128 reads

// ---------------- weight repack to bf16, swizzled [chunk][slot][8] ----------------
__global__ __launch_bounds__(256) void prep_kernel(
    const float* __restrict__ w1, const float* __restrict__ w2, const float* __restrict__ w3,
    __bf16* __restrict__ wb)
{
  int i = blockIdx.x * 256 + threadIdx.x;   // 0..245759 (bf16 elems)
  if (i >= 245760) return;
  int e8   = i & 7;
  int sg   = i >> 3;          // global slot
  int slot = sg & 511;
  int chunk = sg >> 9;        // slab*10 + ks
  int c  = slot >> 2;
  int gq = (slot & 3) ^ ((slot >> 3) & 3);
  int slab = chunk / 10;
  int ks = chunk - slab * 10;
  int e = ks * 32 + gq * 8 + e8;
  float v = 0.f;
  if (e < kE) {
    if (slab == 0)      v = w1[c * kE + e];
    else if (slab <= 2) v = w2[(c * kE + e) * 2 + (slab - 1)];
    else                v = w3[(c * kE + e) * 3 + (slab - 3)];
  }
  wb[i] = (__bf16)v;
}

// async stage one 8 KB weight chunk into LDS (lane-linear; 2 x 16B per lane)
__device__ __forceinline__ void stage_chunk(const __bf16* __restrict__ gchunk,
                                            __bf16* __restrict__ ldst, int w, int l) {
  const __bf16* g0 = gchunk + (size_t)(w * 128 + l) * 8;
  const __bf16* g1 = gchunk + (size_t)(w * 128 + 64 + l) * 8;
  __bf16* l0 = ldst + w * 1024;
  __bf16* l1 = ldst + w * 1024 + 512;
  __builtin_amdgcn_global_load_lds(
      (const __attribute__((address_space(1))) uint32_t*)g0,
      (__attribute__((address_space(3))) uint32_t*)l0, 16, 0, 0);
  __builtin_amdgcn_global_load_lds(
      (const __attribute__((address_space(1))) uint32_t*)g1,
      (__attribute__((address_space(3))) uint32_t*)l1, 16, 0, 0);
}

// ---------------- per-grp MFMA loop: LDS double-buffered weight stream ----------------
// global chunk = CH0 + sg; buffer parity = global chunk & 1. Pre-stages the next grp's
// first chunk during this grp's last step (chunk < 60 guard).
template<int NJ, int CH0>
__device__ __forceinline__ void conv_grp(
    const __bf16* __restrict__ wb, const __bf16* __restrict__ Xs,
    __bf16* __restrict__ Wb0, __bf16* __restrict__ Wb1,
    int w, int l, int lr, int g, int wm, int wn, f4v (&acc)[2][4])
{
  constexpr int N = NJ * 10;
  const int wboff = (wn * 64 + lr) * 32 + (g ^ ((lr >> 1) & 3)) * 8;
  const int arow = wm * 32 + lr;
  const int ae = g * 8;

  #pragma unroll
  for (int sgi = 0; sgi < N; ++sgi) {
    const int chunk = CH0 + sgi;
    __bf16* cur = (chunk & 1) ? Wb1 : Wb0;
    __bf16* nxt = (chunk & 1) ? Wb0 : Wb1;
    if (chunk + 1 < 60)
      stage_chunk(wb + (size_t)(chunk + 1) * 4096, nxt, w, l);
    const int j = sgi / 10, ks = sgi - (sgi / 10) * 10;
    bf8v A0 = *(const bf8v*)&Xs[(arow + j) * XS_STRIDE + ks * 32 + ae];
    bf8v A1 = *(const bf8v*)&Xs[(arow + j + 16) * XS_STRIDE + ks * 32 + ae];
    bf8v W0 = *(const bf8v*)(cur + wboff);
    bf8v W1 = *(const bf8v*)(cur + wboff + 512);
    bf8v W2 = *(const bf8v*)(cur + wboff + 1024);
    bf8v W3 = *(const bf8v*)(cur + wboff + 1536);
    acc[0][0] = __builtin_amdgcn_mfma_f32_16x16x32_bf16(A0, W0, acc[0][0], 0, 0, 0);
    acc[1][0] = __builtin_amdgcn_mfma_f32_16x16x32_bf16(A1, W0, acc[1][0], 0, 0, 0);
    acc[0][1] = __builtin_amdgcn_mfma_f32_16x16x32_bf16(A0, W1, acc[0][1], 0, 0, 0);
    acc[1][1] = __builtin_amdgcn_mfma_f32_16x16x32_bf16(A1, W1, acc[1][1], 0, 0, 0);
    acc[0][2] = __builtin_amdgcn_mfma_f32_16x16x32_bf16(A0, W2, acc[0][2], 0, 0, 0);
    acc[1][2] = __builtin_amdgcn_mfma_f32_16x16x32_bf16(A1, W2, acc[1][2], 0, 0, 0);
    acc[0][3] = __builtin_amdgcn_mfma_f32_16x16x32_bf16(A0, W3, acc[0][3], 0, 0, 0);
    acc[1][3] = __builtin_amdgcn_mfma_f32_16x16x32_bf16(A1, W3, acc[1][3], 0, 0, 0);
    __syncthreads();   // vmcnt(0)+lgkmcnt(0) drain + barrier: next chunk ready, cur reads done
  }
}

// ---------------- fused conv (all 3 widths) + bias + relu + L2-norm -> bf16 [L][C] ----------------
// grid (9, B): x==0 -> query (L=32), x=1..8 -> doc tile (p0=(x-1)*64)
// 256 threads = 4 waves; tile 64 pos x 128 ch; wave (wm,wn) -> rows wm*32+, cols wn*64+
__global__ __launch_bounds__(256, 2) void conv_fused(
    const float* __restrict__ qe, const float* __restrict__ de,
    const __bf16* __restrict__ wb,
    const float* __restrict__ b1, const float* __restrict__ b2, const float* __restrict__ b3,
    __bf16* __restrict__ qnb, __bf16* __restrict__ dnb)
{
  const int bx = blockIdx.x;
  const int b  = blockIdx.y;
  const bool isq = (bx == 0);
  const int L  = isq ? kQ : kD;
  const int p0 = isq ? 0 : (bx - 1) * 64;
  const float* xsrc = (isq ? qe : de) + (size_t)b * L * kE;

  const int t = threadIdx.x;
  const int w = t >> 6, l = t & 63;
  const int wm = w & 1, wn = w >> 1;
  const int lr = l & 15, g = l >> 4;

  __shared__ __align__(16) __bf16 Xs[66 * XS_STRIDE];
  __shared__ __align__(16) __bf16 Wbuf[2][4096];
  __shared__ float sqs[2][64];

  // stage chunk 0 + x tile, one barrier
  stage_chunk(wb, &Wbuf[0][0], w, l);
  for (int idx = t; idx < 66 * 82; idx += 256) {
    int row = idx / 82, c4 = idx - row * 82;
    int gp = p0 + row;
    float4 v = make_float4(0.f, 0.f, 0.f, 0.f);
    if (gp < L && c4 < 75) v = *(const float4*)(xsrc + (size_t)gp * kE + c4 * 4);
    bf4v hv = { (__bf16)v.x, (__bf16)v.y, (__bf16)v.z, (__bf16)v.w };
    *(bf4v*)&Xs[row * XS_STRIDE + c4 * 4] = hv;
  }
  __syncthreads();

  #pragma unroll
  for (int grp = 0; grp < 3; ++grp) {
    f4v acc[2][4];
    #pragma unroll
    for (int mf = 0; mf < 2; ++mf)
      #pragma unroll
      for (int nf = 0; nf < 4; ++nf)
        acc[mf][nf] = (f4v)0.f;

    if (grp == 0)      conv_grp<1, 0>(wb, Xs, &Wbuf[0][0], &Wbuf[1][0], w, l, lr, g, wm, wn, acc);
    else if (grp == 1) conv_grp<2, 10>(wb, Xs, &Wbuf[0][0], &Wbuf[1][0], w, l, lr, g, wm, wn, acc);
    else               conv_grp<3, 30>(wb, Xs, &Wbuf[0][0], &Wbuf[1][0], w, l, lr, g, wm, wn, acc);

    // epilogue: bias + relu + L2 norm over 128 channels
    const float* bias = (grp == 0) ? b1 : ((grp == 1) ? b2 : b3);
    float bvs[4];
    #pragma unroll
    for (int nf = 0; nf < 4; ++nf) bvs[nf] = bias[wn * 64 + nf * 16 + lr];

    f4v ssum[2];
    #pragma unroll
    for (int mf = 0; mf < 2; ++mf) {
      ssum[mf] = (f4v)0.f;
      #pragma unroll
      for (int nf = 0; nf < 4; ++nf)
        #pragma unroll
        for (int r = 0; r < 4; ++r) {
          float y = fmaxf(acc[mf][nf][r] + bvs[nf], 0.f);
          acc[mf][nf][r] = y;
          ssum[mf][r] += y * y;
        }
    }
    #pragma unroll
    for (int off = 1; off < 16; off <<= 1)
      #pragma unroll
      for (int mf = 0; mf < 2; ++mf)
        #pragma unroll
        for (int r = 0; r < 4; ++r)
          ssum[mf][r] += __shfl_xor(ssum[mf][r], off);

    __syncthreads();
    if (lr == 0) {
      #pragma unroll
      for (int mf = 0; mf < 2; ++mf)
        *(float4*)&sqs[wn][wm * 32 + mf * 16 + g * 4] = *(float4*)&ssum[mf];
    }
    __syncthreads();
    f4v inv[2];
    #pragma unroll
    for (int mf = 0; mf < 2; ++mf) {
      float4 o = *(const float4*)&sqs[1 - wn][wm * 32 + mf * 16 + g * 4];
      inv[mf][0] = 1.f / (sqrtf(ssum[mf][0] + o.x) + 1e-13f);
      inv[mf][1] = 1.f / (sqrtf(ssum[mf][1] + o.y) + 1e-13f);
      inv[mf][2] = 1.f / (sqrtf(ssum[mf][2] + o.z) + 1e-13f);
      inv[mf][3] = 1.f / (sqrtf(ssum[mf][3] + o.w) + 1e-13f);
    }
    __syncthreads();   // keep sqs safe for next grp; also separates Wbuf epochs
    // store bf16 [B][L][C]
    __bf16* outp = (isq ? qnb : dnb) + ((size_t)(grp * kB + b)) * L * kC;
    #pragma unroll
    for (int mf = 0; mf < 2; ++mf) {
      #pragma unroll
      for (int r = 0; r < 4; ++r) {
        int gp = p0 + wm * 32 + mf * 16 + g * 4 + r;
        if (gp < L) {
          #pragma unroll
          for (int nf = 0; nf < 4; ++nf) {
            int c = wn * 64 + nf * 16 + lr;
            outp[(size_t)gp * kC + c] = (__bf16)(acc[mf][nf][r] * inv[mf][r]);
          }
        }
      }
    }
  }
}

// ---------------- MFMA cosine + RBF pooling ----------------
// grid (9, B), 256 threads = 4 waves. Per block: S[512 d][32 q] for one (pair,b).
__global__ __launch_bounds__(256) void pool_mfma(
    const __bf16* __restrict__ qnb,  // [3][B][32][128]
    const __bf16* __restrict__ dnb,  // [3][B][512][128]
    const float* __restrict__ qmask, // [B][32]
    const float* __restrict__ dmask, // [B][512]
    float* __restrict__ pkq)         // [9][B][32][11]
{
  const int pair = blockIdx.x;
  const int b = blockIdx.y;
  const int qi = pair / 3, dj = pair - qi * 3;
  const __bf16* qb = qnb + ((size_t)qi * kB + b) * kQ * kC;
  const __bf16* db = dnb + ((size_t)dj * kB + b) * kD * kC;

  const int t = threadIdx.x;
  const int w = t >> 6, l = t & 63;
  const int lr = l & 15, g = l >> 4;

  __shared__ float red[4][2][16][kK];

  bf8v Bq[2][4];
  #pragma unroll
  for (int qt = 0; qt < 2; ++qt)
    #pragma unroll
    for (int kc = 0; kc < 4; ++kc)
      Bq[qt][kc] = *(const bf8v*)&qb[(size_t)(qt * 16 + lr) * kC + kc * 32 + g * 8];

  float qmv[2];
  #pragma unroll
  for (int qt = 0; qt < 2; ++qt) qmv[qt] = qmask[b * kQ + qt * 16 + lr];

  const float c1[10] = { 129.84255368f, 100.98865286f,  72.13475204f,  43.28085123f,  14.42695041f,
                         -14.42695041f, -43.28085123f, -72.13475204f, -100.98865286f, -129.84255368f };
  const float c2[10] = { -58.42914915f, -35.34602850f, -18.03368801f, -6.49212768f, -0.72134752f,
                          -0.72134752f,  -6.49212768f, -18.03368801f, -35.34602850f, -58.42914915f };
  const float C50 = -50.f * LOG2E;
  const float C0  = -500000.f * LOG2E;

  float pk[2][kK];
  #pragma unroll
  for (int qt = 0; qt < 2; ++qt)
    #pragma unroll
    for (int k = 0; k < kK; ++k) pk[qt][k] = 0.f;

  const int dt0 = w * 8;
  bf8v An[4];
  #pragma unroll
  for (int kc = 0; kc < 4; ++kc)
    An[kc] = *(const bf8v*)&db[(size_t)(dt0 * 16 + lr) * kC + kc * 32 + g * 8];

  for (int dtl = 0; dtl < 8; ++dtl) {
    const int drow0 = (dt0 + dtl) * 16;
    bf8v Ac[4];
    #pragma unroll
    for (int kc = 0; kc < 4; ++kc) Ac[kc] = An[kc];
    if (dtl < 7) {
      #pragma unroll
      for (int kc = 0; kc < 4; ++kc)
        An[kc] = *(const bf8v*)&db[(size_t)(drow0 + 16 + lr) * kC + kc * 32 + g * 8];
    }
    f4v acc0 = (f4v)0.f, acc1 = (f4v)0.f;
    #pragma unroll
    for (int kc = 0; kc < 4; ++kc) {
      acc0 = __builtin_amdgcn_mfma_f32_16x16x32_bf16(Ac[kc], Bq[0][kc], acc0, 0, 0, 0);
      acc1 = __builtin_amdgcn_mfma_f32_16x16x32_bf16(Ac[kc], Bq[1][kc], acc1, 0, 0, 0);
    }
    float4 dmv = *(const float4*)&dmask[b * kD + drow0 + g * 4];
    #pragma unroll
    for (int qt = 0; qt < 2; ++qt) {
      const f4v& a = qt ? acc1 : acc0;
      #pragma unroll
      for (int r = 0; r < 4; ++r) {
        float dm = (r == 0) ? dmv.x : (r == 1) ? dmv.y : (r == 2) ? dmv.z : dmv.w;
        float off = fmaf(dm, 1000.f, -1000.f);
        float s = a[r] * qmv[qt] * dm;
        float s2 = s * s;
        float base = fmaf(s2, C50, off);
        float dd = s - 1.f;
        pk[qt][0] += exp2f(fmaf(dd * dd, C0, off));
        #pragma unroll
        for (int k = 0; k < 10; ++k)
          pk[qt][k + 1] += exp2f(fmaf(c1[k], s, base) + c2[k]);
      }
    }
  }

  #pragma unroll
  for (int off = 16; off < 64; off <<= 1)
    #pragma unroll
    for (int qt = 0; qt < 2; ++qt)
      #pragma unroll
      for (int k = 0; k < kK; ++k)
        pk[qt][k] += __shfl_xor(pk[qt][k], off);

  if (l < 16) {
    #pragma unroll
    for (int qt = 0; qt < 2; ++qt)
      #pragma unroll
      for (int k = 0; k < kK; ++k)
        red[w][qt][lr][k] = pk[qt][k];
  }
  __syncthreads();
  for (int i = t; i < 2 * 16 * kK; i += 256) {
    int qt = i / (16 * kK);
    int rem = i - qt * 16 * kK;
    int lq = rem / kK, k = rem - lq * kK;
    float v = red[0][qt][lq][k] + red[1][qt][lq][k] + red[2][qt][lq][k] + red[3][qt][lq][k];
    int q = qt * 16 + lq;
    pkq[(((size_t)pair * kB + b) * kQ + q) * kK + k] = v * qmask[b * kQ + q];
  }
}

// ---------------- log-pool + dense layers ----------------
__global__ __launch_bounds__(128) void finalize_kernel(
    const float* __restrict__ pkq, const float* __restrict__ qmask,
    const float* __restrict__ dmask, const float* __restrict__ nsp,
    const float* __restrict__ dw, const float* __restrict__ dbp,
    const float* __restrict__ dmw, const float* __restrict__ dmbp,
    const float* __restrict__ dcw, float* __restrict__ out)
{
  const int b = blockIdx.x;
  const int t = threadIdx.x;
  __shared__ float sh[4];
  float dl = 0.f;
  for (int d = t; d < kD; d += 128) dl += dmask[b * kD + d];
  #pragma unroll
  for (int off = 1; off < 64; off <<= 1) dl += __shfl_xor(dl, off);
  if ((t & 63) == 0) sh[t >> 6] = dl;
  __syncthreads();
  const float idl = 1.f / (sh[0] + sh[1]);
  const float sc = nsp[0];
  float ps = 0.f, pm = 0.f;
  for (int i = t; i < 99; i += 128) {
    int pr = i / kK, kk = i - pr * kK;
    const float* base = pkq + ((size_t)pr * kB + b) * kQ * kK + kk;
    float ss = 0.f, sm = 0.f;
    for (int q = 0; q < kQ; ++q) {
      float v = base[q * kK];
      float qq = qmask[b * kQ + q];
      ss += __logf(fmaxf(v, 1e-10f)) * qq;
      sm += __logf(fmaxf(v * idl, 1e-10f)) * qq;
    }
    ps += dw[i] * ss;
    pm += dmw[i] * sm;
  }
  ps *= sc; pm *= sc;
  #pragma unroll
  for (int off = 1; off < 64; off <<= 1) { ps += __shfl_xor(ps, off); pm += __shfl_xor(pm, off); }
  __syncthreads();
  if ((t & 63) == 0) { sh[t >> 6] = ps; sh[2 + (t >> 6)] = pm; }
  __syncthreads();
  if (t == 0) {
    float PS = sh[0] + sh[1] + dbp[0];
    float PM = sh[2] + sh[3] + dmbp[0];
    out[b] = dcw[0] * PS + dcw[1] * PM;
  }
}

} // namespace

extern "C" void kernel_launch(void* const* d_in, const int* in_sizes, int n_in,
                              void* d_out, int out_size, void* d_ws, size_t ws_size,
                              hipStream_t stream) {
  const float* qe  = (const float*)d_in[0];
  const float* de  = (const float*)d_in[1];
  const float* qm  = (const float*)d_in[2];
  const float* dm  = (const float*)d_in[3];
  const float* w1  = (const float*)d_in[4];
  const float* b1  = (const float*)d_in[5];
  const float* w2  = (const float*)d_in[6];
  const float* b2  = (const float*)d_in[7];
  const float* w3  = (const float*)d_in[8];
  const float* b3  = (const float*)d_in[9];
  const float* ns  = (const float*)d_in[10];
  const float* dw  = (const float*)d_in[11];
  const float* db  = (const float*)d_in[12];
  const float* dmw = (const float*)d_in[13];
  const float* dmb = (const float*)d_in[14];
  const float* dcw = (const float*)d_in[15];
  float* out = (float*)d_out;

  char* wsb = (char*)d_ws;
  __bf16* wb  = (__bf16*)wsb;
  __bf16* qnb = (__bf16*)(wsb + QNB_B);
  __bf16* dnb = (__bf16*)(wsb + DNB_B);
  float*  pkq = (float*)(wsb + PKQ_B);

  prep_kernel<<<960, 256, 0, stream>>>(w1, w2, w3, wb);
  conv_fused<<<dim3(9, kB), 256, 0, stream>>>(qe, de, wb, b1, b2, b3, qnb, dnb);
  pool_mfma<<<dim3(9, kB), 256, 0, stream>>>(qnb, dnb, qm, dm, pkq);
  finalize_kernel<<<kB, 128, 0, stream>>>(pkq, qm, dm, ns, dw, db, dmw, dmb, dcw, out);
}

// Round 9
// 166.849 us; speedup vs baseline: 1.0966x; 1.0571x over previous
//
#include <hip/hip_runtime.h>
#include <hip/hip_bf16.h>
#include <cstdint>

namespace {

typedef __bf16 bf8v __attribute__((ext_vector_type(8)));
typedef __bf16 bf4v __attribute__((ext_vector_type(4)));
typedef float  f4v  __attribute__((ext_vector_type(4)));
typedef uint32_t u32x4 __attribute__((ext_vector_type(4)));

constexpr int kB = 128;   // batch
constexpr int kQ = 32;    // query len
constexpr int kD = 512;   // doc len
constexpr int kE = 300;   // embed dim
constexpr int kC = 128;   // conv channels
constexpr int kK = 11;    // RBF kernels

// workspace layout (bytes)
// wb:  [60 chunks][128 c][32 e] bf16 = 491520 B, chunk = slab*10+ks (c1j0|c2j0,j1|c3j0,j1,j2)
// qnb: [3][B][32][128]  bf16   dnb: [3][B][512][128] bf16   pkq: [9][B][32][11] f32
constexpr size_t QNB_B = 491520;
constexpr size_t DNB_B = 3637248;
constexpr size_t PKQ_B = 53968896;

constexpr float LOG2E = 1.4426950408889634f;

constexpr int XS_STRIDE = 336;   // elems; 672 B row stride

// ---------------- weight repack to bf16 [chunk][c][32] ----------------
__global__ __launch_bounds__(256) void prep_kernel(
    const float* __restrict__ w1, const float* __restrict__ w2, const float* __restrict__ w3,
    __bf16* __restrict__ wb)
{
  int i = blockIdx.x * 256 + threadIdx.x;   // 0..245759
  if (i >= 245760) return;
  int el = i & 31;
  int sc = i >> 5;              // chunk*128 + c
  int c  = sc & 127;
  int chunk = sc >> 7;          // slab*10 + ks
  int slab = chunk / 10;
  int ks = chunk - slab * 10;
  int e = ks * 32 + el;
  float v = 0.f;
  if (e < kE) {
    if (slab == 0)      v = w1[c * kE + e];
    else if (slab <= 2) v = w2[(c * kE + e) * 2 + (slab - 1)];
    else                v = w3[(c * kE + e) * 3 + (slab - 3)];
  }
  wb[i] = (__bf16)v;
}

// -------- counted-vmcnt async load machinery --------
template<int VM>
__device__ __forceinline__ void wait_vm() {
  if constexpr (VM == 4) asm volatile("s_waitcnt vmcnt(4)" ::: "memory");
  else                   asm volatile("s_waitcnt vmcnt(0)" ::: "memory");
  __builtin_amdgcn_sched_barrier(0);
}

// issue one 4-fragment W batch (4 x 16B per lane, literal offsets)
__device__ __forceinline__ void issue4(u32x4 (&Wset)[4], const __bf16* p) {
  asm volatile("global_load_dwordx4 %0, %1, off"             : "=v"(Wset[0]) : "v"(p) : "memory");
  asm volatile("global_load_dwordx4 %0, %1, off offset:1024" : "=v"(Wset[1]) : "v"(p) : "memory");
  asm volatile("global_load_dwordx4 %0, %1, off offset:2048" : "=v"(Wset[2]) : "v"(p) : "memory");
  asm volatile("global_load_dwordx4 %0, %1, off offset:3072" : "=v"(Wset[3]) : "v"(p) : "memory");
}

__device__ __forceinline__ void mfma8(bf8v A0, bf8v A1, u32x4 (&Ws)[4], f4v (&acc)[2][4]) {
  #pragma unroll
  for (int nf = 0; nf < 4; ++nf) {
    bf8v Wf = __builtin_bit_cast(bf8v, Ws[nf]);
    acc[0][nf] = __builtin_amdgcn_mfma_f32_16x16x32_bf16(A0, Wf, acc[0][nf], 0, 0, 0);
    acc[1][nf] = __builtin_amdgcn_mfma_f32_16x16x32_bf16(A1, Wf, acc[1][nf], 0, 0, 0);
  }
}

// ---------------- per-grp loop: depth-2 register pipeline, rolled, no barriers ----------------
// steady step: wait vmcnt(4) -> batch s landed; 8 MFMA; issue batch s+2. Tail waits 4, 0.
template<int NJ, int CH0>
__device__ __forceinline__ void conv_grp(
    const __bf16* __restrict__ wb, const __bf16* __restrict__ Xs,
    int lr, int g, int wm, int wn, f4v (&acc)[2][4])
{
  const __bf16* wl = wb + (size_t)CH0 * 4096 + (wn * 64 + lr) * 32 + g * 8;
  const int arow = wm * 32 + lr;
  const int ae = g * 8;

  u32x4 W0[4], W1[4];
  issue4(W0, wl);            // batch 0
  issue4(W1, wl + 4096);     // batch 1
  const __bf16* wnext = wl + 2 * 4096;

  #pragma unroll
  for (int j = 0; j < NJ; ++j) {
    const __bf16* xr = Xs + (size_t)(arow + j) * XS_STRIDE + ae;
    const int nks = (j == NJ - 1) ? 8 : 10;   // last j leaves 2 drain steps
    #pragma unroll 1
    for (int ks = 0; ks < nks; ks += 2) {
      bf8v A0 = *(const bf8v*)(xr + ks * 32);
      bf8v A1 = *(const bf8v*)(xr + 16 * XS_STRIDE + ks * 32);
      wait_vm<4>();
      mfma8(A0, A1, W0, acc);
      issue4(W0, wnext); wnext += 4096;
      bf8v B0 = *(const bf8v*)(xr + ks * 32 + 32);
      bf8v B1 = *(const bf8v*)(xr + 16 * XS_STRIDE + ks * 32 + 32);
      wait_vm<4>();
      mfma8(B0, B1, W1, acc);
      issue4(W1, wnext); wnext += 4096;
    }
  }
  // drain: steps ks=8,9 of last j
  const __bf16* xr = Xs + (size_t)(arow + NJ - 1) * XS_STRIDE + ae;
  bf8v A0 = *(const bf8v*)(xr + 8 * 32);
  bf8v A1 = *(const bf8v*)(xr + 16 * XS_STRIDE + 8 * 32);
  wait_vm<4>();
  mfma8(A0, A1, W0, acc);
  bf8v B0 = *(const bf8v*)(xr + 9 * 32);
  bf8v B1 = *(const bf8v*)(xr + 16 * XS_STRIDE + 9 * 32);
  wait_vm<0>();
  mfma8(B0, B1, W1, acc);
}

// ---------------- fused conv (all 3 widths) + bias + relu + L2-norm -> bf16 [L][C] ----------------
// grid (9, B): x==0 -> query (L=32), x=1..8 -> doc tile (p0=(x-1)*64)
// 256 threads = 4 waves; tile 64 pos x 128 ch; wave (wm,wn) -> rows wm*32+, cols wn*64+
__global__ __launch_bounds__(256, 3) void conv_fused(
    const float* __restrict__ qe, const float* __restrict__ de,
    const __bf16* __restrict__ wb,
    const float* __restrict__ b1, const float* __restrict__ b2, const float* __restrict__ b3,
    __bf16* __restrict__ qnb, __bf16* __restrict__ dnb)
{
  const int bx = blockIdx.x;
  const int b  = blockIdx.y;
  const bool isq = (bx == 0);
  const int L  = isq ? kQ : kD;
  const int p0 = isq ? 0 : (bx - 1) * 64;
  const float* xsrc = (isq ? qe : de) + (size_t)b * L * kE;

  const int t = threadIdx.x;
  const int w = t >> 6, l = t & 63;
  const int wm = w & 1, wn = w >> 1;
  const int lr = l & 15, g = l >> 4;

  __shared__ __align__(16) __bf16 Xs[66 * XS_STRIDE];
  __shared__ float sqs[2][64];

  // stage x rows p0..p0+65, e 0..327 (zero-pad) as bf16
  for (int idx = t; idx < 66 * 82; idx += 256) {
    int row = idx / 82, c4 = idx - row * 82;
    int gp = p0 + row;
    float4 v = make_float4(0.f, 0.f, 0.f, 0.f);
    if (gp < L && c4 < 75) v = *(const float4*)(xsrc + (size_t)gp * kE + c4 * 4);
    bf4v hv = { (__bf16)v.x, (__bf16)v.y, (__bf16)v.z, (__bf16)v.w };
    *(bf4v*)&Xs[row * XS_STRIDE + c4 * 4] = hv;
  }
  __syncthreads();

  #pragma unroll
  for (int grp = 0; grp < 3; ++grp) {
    f4v acc[2][4];
    #pragma unroll
    for (int mf = 0; mf < 2; ++mf)
      #pragma unroll
      for (int nf = 0; nf < 4; ++nf)
        acc[mf][nf] = (f4v)0.f;

    if (grp == 0)      conv_grp<1, 0>(wb, Xs, lr, g, wm, wn, acc);
    else if (grp == 1) conv_grp<2, 10>(wb, Xs, lr, g, wm, wn, acc);
    else               conv_grp<3, 30>(wb, Xs, lr, g, wm, wn, acc);

    // epilogue: bias + relu + L2 norm over 128 channels
    const float* bias = (grp == 0) ? b1 : ((grp == 1) ? b2 : b3);
    float bvs[4];
    #pragma unroll
    for (int nf = 0; nf < 4; ++nf) bvs[nf] = bias[wn * 64 + nf * 16 + lr];

    f4v ssum[2];
    #pragma unroll
    for (int mf = 0; mf < 2; ++mf) {
      ssum[mf] = (f4v)0.f;
      #pragma unroll
      for (int nf = 0; nf < 4; ++nf)
        #pragma unroll
        for (int r = 0; r < 4; ++r) {
          float y = fmaxf(acc[mf][nf][r] + bvs[nf], 0.f);
          acc[mf][nf][r] = y;
          ssum[mf][r] += y * y;
        }
    }
    #pragma unroll
    for (int off = 1; off < 16; off <<= 1)
      #pragma unroll
      for (int mf = 0; mf < 2; ++mf)
        #pragma unroll
        for (int r = 0; r < 4; ++r)
          ssum[mf][r] += __shfl_xor(ssum[mf][r], off);

    __syncthreads();
    if (lr == 0) {
      #pragma unroll
      for (int mf = 0; mf < 2; ++mf)
        *(float4*)&sqs[wn][wm * 32 + mf * 16 + g * 4] = *(float4*)&ssum[mf];
    }
    __syncthreads();
    f4v inv[2];
    #pragma unroll
    for (int mf = 0; mf < 2; ++mf) {
      float4 o = *(const float4*)&sqs[1 - wn][wm * 32 + mf * 16 + g * 4];
      inv[mf][0] = 1.f / (sqrtf(ssum[mf][0] + o.x) + 1e-13f);
      inv[mf][1] = 1.f / (sqrtf(ssum[mf][1] + o.y) + 1e-13f);
      inv[mf][2] = 1.f / (sqrtf(ssum[mf][2] + o.z) + 1e-13f);
      inv[mf][3] = 1.f / (sqrtf(ssum[mf][3] + o.w) + 1e-13f);
    }
    __syncthreads();
    // store bf16 [B][L][C]
    __bf16* outp = (isq ? qnb : dnb) + ((size_t)(grp * kB + b)) * L * kC;
    #pragma unroll
    for (int mf = 0; mf < 2; ++mf) {
      #pragma unroll
      for (int r = 0; r < 4; ++r) {
        int gp = p0 + wm * 32 + mf * 16 + g * 4 + r;
        if (gp < L) {
          #pragma unroll
          for (int nf = 0; nf < 4; ++nf) {
            int c = wn * 64 + nf * 16 + lr;
            outp[(size_t)gp * kC + c] = (__bf16)(acc[mf][nf][r] * inv[mf][r]);
          }
        }
      }
    }
  }
}

// ---------------- MFMA cosine + RBF pooling ----------------
// grid (9, B), 256 threads = 4 waves. Per block: S[512 d][32 q] for one (pair,b).
__global__ __launch_bounds__(256) void pool_mfma(
    const __bf16* __restrict__ qnb,  // [3][B][32][128]
    const __bf16* __restrict__ dnb,  // [3][B][512][128]
    const float* __restrict__ qmask, // [B][32]
    const float* __restrict__ dmask, // [B][512]
    float* __restrict__ pkq)         // [9][B][32][11]
{
  const int pair = blockIdx.x;
  const int b = blockIdx.y;
  const int qi = pair / 3, dj = pair - qi * 3;
  const __bf16* qb = qnb + ((size_t)qi * kB + b) * kQ * kC;
  const __bf16* db = dnb + ((size_t)dj * kB + b) * kD * kC;

  const int t = threadIdx.x;
  const int w = t >> 6, l = t & 63;
  const int lr = l & 15, g = l >> 4;

  __shared__ float red[4][2][16][kK];

  bf8v Bq[2][4];
  #pragma unroll
  for (int qt = 0; qt < 2; ++qt)
    #pragma unroll
    for (int kc = 0; kc < 4; ++kc)
      Bq[qt][kc] = *(const bf8v*)&qb[(size_t)(qt * 16 + lr) * kC + kc * 32 + g * 8];

  float qmv[2];
  #pragma unroll
  for (int qt = 0; qt < 2; ++qt) qmv[qt] = qmask[b * kQ + qt * 16 + lr];

  const float c1[10] = { 129.84255368f, 100.98865286f,  72.13475204f,  43.28085123f,  14.42695041f,
                         -14.42695041f, -43.28085123f, -72.13475204f, -100.98865286f, -129.84255368f };
  const float c2[10] = { -58.42914915f, -35.34602850f, -18.03368801f, -6.49212768f, -0.72134752f,
                          -0.72134752f,  -6.49212768f, -18.03368801f, -35.34602850f, -58.42914915f };
  const float C50 = -50.f * LOG2E;
  const float C0  = -500000.f * LOG2E;

  float pk[2][kK];
  #pragma unroll
  for (int qt = 0; qt < 2; ++qt)
    #pragma unroll
    for (int k = 0; k < kK; ++k) pk[qt][k] = 0.f;

  const int dt0 = w * 8;
  bf8v An[4];
  #pragma unroll
  for (int kc = 0; kc < 4; ++kc)
    An[kc] = *(const bf8v*)&db[(size_t)(dt0 * 16 + lr) * kC + kc * 32 + g * 8];

  for (int dtl = 0; dtl < 8; ++dtl) {
    const int drow0 = (dt0 + dtl) * 16;
    bf8v Ac[4];
    #pragma unroll
    for (int kc = 0; kc < 4; ++kc) Ac[kc] = An[kc];
    if (dtl < 7) {
      #pragma unroll
      for (int kc = 0; kc < 4; ++kc)
        An[kc] = *(const bf8v*)&db[(size_t)(drow0 + 16 + lr) * kC + kc * 32 + g * 8];
    }
    f4v acc0 = (f4v)0.f, acc1 = (f4v)0.f;
    #pragma unroll
    for (int kc = 0; kc < 4; ++kc) {
      acc0 = __builtin_amdgcn_mfma_f32_16x16x32_bf16(Ac[kc], Bq[0][kc], acc0, 0, 0, 0);
      acc1 = __builtin_amdgcn_mfma_f32_16x16x32_bf16(Ac[kc], Bq[1][kc], acc1, 0, 0, 0);
    }
    float4 dmv = *(const float4*)&dmask[b * kD + drow0 + g * 4];
    #pragma unroll
    for (int qt = 0; qt < 2; ++qt) {
      const f4v& a = qt ? acc1 : acc0;
      #pragma unroll
      for (int r = 0; r < 4; ++r) {
        float dm = (r == 0) ? dmv.x : (r == 1) ? dmv.y : (r == 2) ? dmv.z : dmv.w;
        float off = fmaf(dm, 1000.f, -1000.f);
        float s = a[r] * qmv[qt] * dm;
        float s2 = s * s;
        float base = fmaf(s2, C50, off);
        float dd = s - 1.f;
        pk[qt][0] += exp2f(fmaf(dd * dd, C0, off));
        #pragma unroll
        for (int k = 0; k < 10; ++k)
          pk[qt][k + 1] += exp2f(fmaf(c1[k], s, base) + c2[k]);
      }
    }
  }

  #pragma unroll
  for (int off = 16; off < 64; off <<= 1)
    #pragma unroll
    for (int qt = 0; qt < 2; ++qt)
      #pragma unroll
      for (int k = 0; k < kK; ++k)
        pk[qt][k] += __shfl_xor(pk[qt][k], off);

  if (l < 16) {
    #pragma unroll
    for (int qt = 0; qt < 2; ++qt)
      #pragma unroll
      for (int k = 0; k < kK; ++k)
        red[w][qt][lr][k] = pk[qt][k];
  }
  __syncthreads();
  for (int i = t; i < 2 * 16 * kK; i += 256) {
    int qt = i / (16 * kK);
    int rem = i - qt * 16 * kK;
    int lq = rem / kK, k = rem - lq * kK;
    float v = red[0][qt][lq][k] + red[1][qt][lq][k] + red[2][qt][lq][k] + red[3][qt][lq][k];
    int q = qt * 16 + lq;
    pkq[(((size_t)pair * kB + b) * kQ + q) * kK + k] = v * qmask[b * kQ + q];
  }
}

// ---------------- log-pool + dense layers ----------------
__global__ __launch_bounds__(128) void finalize_kernel(
    const float* __restrict__ pkq, const float* __restrict__ qmask,
    const float* __restrict__ dmask, const float* __restrict__ nsp,
    const float* __restrict__ dw, const float* __restrict__ dbp,
    const float* __restrict__ dmw, const float* __restrict__ dmbp,
    const float* __restrict__ dcw, float* __restrict__ out)
{
  const int b = blockIdx.x;
  const int t = threadIdx.x;
  __shared__ float sh[4];
  float dl = 0.f;
  for (int d = t; d < kD; d += 128) dl += dmask[b * kD + d];
  #pragma unroll
  for (int off = 1; off < 64; off <<= 1) dl += __shfl_xor(dl, off);
  if ((t & 63) == 0) sh[t >> 6] = dl;
  __syncthreads();
  const float idl = 1.f / (sh[0] + sh[1]);
  const float sc = nsp[0];
  float ps = 0.f, pm = 0.f;
  for (int i = t; i < 99; i += 128) {
    int pr = i / kK, kk = i - pr * kK;
    const float* base = pkq + ((size_t)pr * kB + b) * kQ * kK + kk;
    float ss = 0.f, sm = 0.f;
    for (int q = 0; q < kQ; ++q) {
      float v = base[q * kK];
      float qq = qmask[b * kQ + q];
      ss += __logf(fmaxf(v, 1e-10f)) * qq;
      sm += __logf(fmaxf(v * idl, 1e-10f)) * qq;
    }
    ps += dw[i] * ss;
    pm += dmw[i] * sm;
  }
  ps *= sc; pm *= sc;
  #pragma unroll
  for (int off = 1; off < 64; off <<= 1) { ps += __shfl_xor(ps, off); pm += __shfl_xor(pm, off); }
  __syncthreads();
  if ((t & 63) == 0) { sh[t >> 6] = ps; sh[2 + (t >> 6)] = pm; }
  __syncthreads();
  if (t == 0) {
    float PS = sh[0] + sh[1] + dbp[0];
    float PM = sh[2] + sh[3] + dmbp[0];
    out[b] = dcw[0] * PS + dcw[1] * PM;
  }
}

} // namespace

extern "C" void kernel_launch(void* const* d_in, const int* in_sizes, int n_in,
                              void* d_out, int out_size, void* d_ws, size_t ws_size,
                              hipStream_t stream) {
  const float* qe  = (const float*)d_in[0];
  const float* de  = (const float*)d_in[1];
  const float* qm  = (const float*)d_in[2];
  const float* dm  = (const float*)d_in[3];
  const float* w1  = (const float*)d_in[4];
  const float* b1  = (const float*)d_in[5];
  const float* w2  = (const float*)d_in[6];
  const float* b2  = (const float*)d_in[7];
  const float* w3  = (const float*)d_in[8];
  const float* b3  = (const float*)d_in[9];
  const float* ns  = (const float*)d_in[10];
  const float* dw  = (const float*)d_in[11];
  const float* db  = (const float*)d_in[12];
  const float* dmw = (const float*)d_in[13];
  const float* dmb = (const float*)d_in[14];
  const float* dcw = (const float*)d_in[15];
  float* out = (float*)d_out;

  char* wsb = (char*)d_ws;
  __bf16* wb  = (__bf16*)wsb;
  __bf16* qnb = (__bf16*)(wsb + QNB_B);
  __bf16* dnb = (__bf16*)(wsb + DNB_B);
  float*  pkq = (float*)(wsb + PKQ_B);

  prep_kernel<<<960, 256, 0, stream>>>(w1, w2, w3, wb);
  conv_fused<<<dim3(9, kB), 256, 0, stream>>>(qe, de, wb, b1, b2, b3, qnb, dnb);
  pool_mfma<<<dim3(9, kB), 256, 0, stream>>>(qnb, dnb, qm, dm, pkq);
  finalize_kernel<<<kB, 128, 0, stream>>>(pkq, qm, dm, ns, dw, db, dmw, dmb, dcw, out);
}

// Round 10
// 162.713 us; speedup vs baseline: 1.1245x; 1.0254x over previous
//
#include <hip/hip_runtime.h>
#include <hip/hip_bf16.h>
#include <cstdint>

namespace {

typedef __bf16 bf8v __attribute__((ext_vector_type(8)));
typedef __bf16 bf4v __attribute__((ext_vector_type(4)));
typedef float  f4v  __attribute__((ext_vector_type(4)));
typedef uint32_t u32x4 __attribute__((ext_vector_type(4)));

constexpr int kB = 128;   // batch
constexpr int kQ = 32;    // query len
constexpr int kD = 512;   // doc len
constexpr int kE = 300;   // embed dim
constexpr int kC = 128;   // conv channels
constexpr int kK = 11;    // RBF kernels

// workspace layout (bytes)
// wb:  [60 chunks][128 c][32 e] bf16 = 491520 B, chunk = slab*10+ks (c1j0|c2j0,j1|c3j0,j1,j2)
// qnb: [3][B][32][128]  bf16   dnb: [3][B][512][128] bf16   pkq: [9][B][32][11] f32
constexpr size_t QNB_B = 491520;
constexpr size_t DNB_B = 3637248;
constexpr size_t PKQ_B = 53968896;

constexpr float LOG2E = 1.4426950408889634f;

constexpr int XS_STRIDE = 336;   // elems; 672 B row stride
constexpr int TB_STRIDE = 136;   // tbuf row stride (128 + 8 pad) -> 4-way write conflicts

// ---------------- weight repack to bf16 [chunk][c][32] ----------------
__global__ __launch_bounds__(256) void prep_kernel(
    const float* __restrict__ w1, const float* __restrict__ w2, const float* __restrict__ w3,
    __bf16* __restrict__ wb)
{
  int i = blockIdx.x * 256 + threadIdx.x;   // 0..245759
  if (i >= 245760) return;
  int el = i & 31;
  int sc = i >> 5;              // chunk*128 + c
  int c  = sc & 127;
  int chunk = sc >> 7;          // slab*10 + ks
  int slab = chunk / 10;
  int ks = chunk - slab * 10;
  int e = ks * 32 + el;
  float v = 0.f;
  if (e < kE) {
    if (slab == 0)      v = w1[c * kE + e];
    else if (slab <= 2) v = w2[(c * kE + e) * 2 + (slab - 1)];
    else                v = w3[(c * kE + e) * 3 + (slab - 3)];
  }
  wb[i] = (__bf16)v;
}

// -------- counted-vmcnt async load machinery (r9-proven structure, 2-load batches) --------
template<int VM>
__device__ __forceinline__ void wait_vm() {
  if constexpr (VM == 2) asm volatile("s_waitcnt vmcnt(2)" ::: "memory");
  else                   asm volatile("s_waitcnt vmcnt(0)" ::: "memory");
  __builtin_amdgcn_sched_barrier(0);
}

__device__ __forceinline__ void issue2(u32x4 (&Wset)[2], const __bf16* p) {
  asm volatile("global_load_dwordx4 %0, %1, off"             : "=v"(Wset[0]) : "v"(p) : "memory");
  asm volatile("global_load_dwordx4 %0, %1, off offset:1024" : "=v"(Wset[1]) : "v"(p) : "memory");
}

__device__ __forceinline__ void mfma4(bf8v A0, bf8v A1, u32x4 (&Ws)[2], f4v (&acc)[2][2]) {
  #pragma unroll
  for (int nf = 0; nf < 2; ++nf) {
    bf8v Wf = __builtin_bit_cast(bf8v, Ws[nf]);
    acc[0][nf] = __builtin_amdgcn_mfma_f32_16x16x32_bf16(A0, Wf, acc[0][nf], 0, 0, 0);
    acc[1][nf] = __builtin_amdgcn_mfma_f32_16x16x32_bf16(A1, Wf, acc[1][nf], 0, 0, 0);
  }
}

// ---------------- per-grp loop: depth-2 register pipeline, rolled, no barriers ----------------
// wave w owns ch slice [w*32, w*32+32): 2 n-frags. steady: wait vmcnt(2) -> batch s landed.
template<int NJ, int CH0>
__device__ __forceinline__ void conv_grp(
    const __bf16* __restrict__ wb, const __bf16* __restrict__ Xs,
    int w, int lr, int g, f4v (&acc)[2][2])
{
  const __bf16* wl = wb + (size_t)CH0 * 4096 + (w * 32 + lr) * 32 + g * 8;
  const int ae = g * 8;

  u32x4 W0[2], W1[2];
  issue2(W0, wl);            // batch 0
  issue2(W1, wl + 4096);     // batch 1
  const __bf16* wnext = wl + 2 * 4096;

  #pragma unroll
  for (int j = 0; j < NJ; ++j) {
    const __bf16* xr = Xs + (size_t)(lr + j) * XS_STRIDE + ae;
    const int nks = (j == NJ - 1) ? 8 : 10;   // last j leaves 2 drain steps
    #pragma unroll 1
    for (int ks = 0; ks < nks; ks += 2) {
      bf8v A0 = *(const bf8v*)(xr + ks * 32);
      bf8v A1 = *(const bf8v*)(xr + 16 * XS_STRIDE + ks * 32);
      wait_vm<2>();
      mfma4(A0, A1, W0, acc);
      issue2(W0, wnext); wnext += 4096;
      bf8v B0 = *(const bf8v*)(xr + ks * 32 + 32);
      bf8v B1 = *(const bf8v*)(xr + 16 * XS_STRIDE + ks * 32 + 32);
      wait_vm<2>();
      mfma4(B0, B1, W1, acc);
      issue2(W1, wnext); wnext += 4096;
    }
  }
  // drain: steps ks=8,9 of last j
  const __bf16* xr = Xs + (size_t)(lr + NJ - 1) * XS_STRIDE + ae;
  bf8v A0 = *(const bf8v*)(xr + 8 * 32);
  bf8v A1 = *(const bf8v*)(xr + 16 * XS_STRIDE + 8 * 32);
  wait_vm<2>();
  mfma4(A0, A1, W0, acc);
  bf8v B0 = *(const bf8v*)(xr + 9 * 32);
  bf8v B1 = *(const bf8v*)(xr + 16 * XS_STRIDE + 9 * 32);
  wait_vm<0>();
  mfma4(B0, B1, W1, acc);
}

// ---------------- fused conv (all 3 widths) + bias + relu + L2-norm -> bf16 [L][C] ----------------
// grid (17, B): x==0 -> query (32 pos), x=1..16 -> doc tile p0=(x-1)*32
// 256 threads = 4 waves; tile 32 pos x 128 ch; wave w -> all 32 pos, ch [w*32, w*32+32)
__global__ __launch_bounds__(256, 5) void conv_fused(
    const float* __restrict__ qe, const float* __restrict__ de,
    const __bf16* __restrict__ wb,
    const float* __restrict__ b1, const float* __restrict__ b2, const float* __restrict__ b3,
    __bf16* __restrict__ qnb, __bf16* __restrict__ dnb)
{
  const int bx = blockIdx.x;
  const int b  = blockIdx.y;
  const bool isq = (bx == 0);
  const int L  = isq ? kQ : kD;
  const int p0 = isq ? 0 : (bx - 1) * 32;
  const float* xsrc = (isq ? qe : de) + (size_t)b * L * kE;

  const int t = threadIdx.x;
  const int w = t >> 6, l = t & 63;
  const int lr = l & 15, g = l >> 4;

  __shared__ __align__(16) __bf16 Xs[34 * XS_STRIDE];
  __shared__ __align__(16) __bf16 tbuf[32 * TB_STRIDE];
  __shared__ float sqs4[4][32];

  // stage x rows p0..p0+33, e 0..327 (zero-pad) as bf16
  for (int idx = t; idx < 34 * 82; idx += 256) {
    int row = idx / 82, c4 = idx - row * 82;
    int gp = p0 + row;
    float4 v = make_float4(0.f, 0.f, 0.f, 0.f);
    if (gp < L && c4 < 75) v = *(const float4*)(xsrc + (size_t)gp * kE + c4 * 4);
    bf4v hv = { (__bf16)v.x, (__bf16)v.y, (__bf16)v.z, (__bf16)v.w };
    *(bf4v*)&Xs[row * XS_STRIDE + c4 * 4] = hv;
  }
  __syncthreads();

  #pragma unroll
  for (int grp = 0; grp < 3; ++grp) {
    f4v acc[2][2];
    #pragma unroll
    for (int mf = 0; mf < 2; ++mf)
      #pragma unroll
      for (int nf = 0; nf < 2; ++nf)
        acc[mf][nf] = (f4v)0.f;

    if (grp == 0)      conv_grp<1, 0>(wb, Xs, w, lr, g, acc);
    else if (grp == 1) conv_grp<2, 10>(wb, Xs, w, lr, g, acc);
    else               conv_grp<3, 30>(wb, Xs, w, lr, g, acc);

    // epilogue: bias + relu + L2 norm over 128 channels (cross-wave via sqs4)
    const float* bias = (grp == 0) ? b1 : ((grp == 1) ? b2 : b3);
    float bvs[2];
    #pragma unroll
    for (int nf = 0; nf < 2; ++nf) bvs[nf] = bias[w * 32 + nf * 16 + lr];

    f4v ssum[2];
    #pragma unroll
    for (int mf = 0; mf < 2; ++mf) {
      ssum[mf] = (f4v)0.f;
      #pragma unroll
      for (int nf = 0; nf < 2; ++nf)
        #pragma unroll
        for (int r = 0; r < 4; ++r) {
          float y = fmaxf(acc[mf][nf][r] + bvs[nf], 0.f);
          acc[mf][nf][r] = y;
          ssum[mf][r] += y * y;
        }
    }
    #pragma unroll
    for (int off = 1; off < 16; off <<= 1)
      #pragma unroll
      for (int mf = 0; mf < 2; ++mf)
        #pragma unroll
        for (int r = 0; r < 4; ++r)
          ssum[mf][r] += __shfl_xor(ssum[mf][r], off);

    if (lr == 0) {
      #pragma unroll
      for (int mf = 0; mf < 2; ++mf)
        *(float4*)&sqs4[w][mf * 16 + g * 4] = *(float4*)&ssum[mf];
    }
    __syncthreads();
    float inv[2][4];
    #pragma unroll
    for (int mf = 0; mf < 2; ++mf)
      #pragma unroll
      for (int r = 0; r < 4; ++r) {
        int row = mf * 16 + g * 4 + r;
        float s = sqs4[0][row] + sqs4[1][row] + sqs4[2][row] + sqs4[3][row];
        inv[mf][r] = 1.f / (sqrtf(s) + 1e-13f);
      }
    // normalized tile -> tbuf (row-major, padded stride)
    #pragma unroll
    for (int mf = 0; mf < 2; ++mf)
      #pragma unroll
      for (int nf = 0; nf < 2; ++nf)
        #pragma unroll
        for (int r = 0; r < 4; ++r) {
          int row = mf * 16 + g * 4 + r;
          int c = w * 32 + nf * 16 + lr;
          tbuf[row * TB_STRIDE + c] = (__bf16)(acc[mf][nf][r] * inv[mf][r]);
        }
    __syncthreads();
    // coalesced store: 512 x 16B contiguous
    __bf16* outp = (isq ? qnb : dnb) + ((size_t)(grp * kB + b)) * L * kC + (size_t)p0 * kC;
    #pragma unroll
    for (int ci = t; ci < 512; ci += 256) {
      bf8v v = *(const bf8v*)&tbuf[(ci >> 4) * TB_STRIDE + (ci & 15) * 8];
      *(bf8v*)(outp + ci * 8) = v;
    }
    asm volatile("s_waitcnt vmcnt(0)" ::: "memory");   // keep counted waits clean next grp
    __syncthreads();
  }
}

// ---------------- MFMA cosine + RBF pooling ----------------
// grid (9, B), 256 threads = 4 waves. Per block: S[512 d][32 q] for one (pair,b).
__global__ __launch_bounds__(256) void pool_mfma(
    const __bf16* __restrict__ qnb,  // [3][B][32][128]
    const __bf16* __restrict__ dnb,  // [3][B][512][128]
    const float* __restrict__ qmask, // [B][32]
    const float* __restrict__ dmask, // [B][512]
    float* __restrict__ pkq)         // [9][B][32][11]
{
  const int pair = blockIdx.x;
  const int b = blockIdx.y;
  const int qi = pair / 3, dj = pair - qi * 3;
  const __bf16* qb = qnb + ((size_t)qi * kB + b) * kQ * kC;
  const __bf16* db = dnb + ((size_t)dj * kB + b) * kD * kC;

  const int t = threadIdx.x;
  const int w = t >> 6, l = t & 63;
  const int lr = l & 15, g = l >> 4;

  __shared__ float red[4][2][16][kK];

  bf8v Bq[2][4];
  #pragma unroll
  for (int qt = 0; qt < 2; ++qt)
    #pragma unroll
    for (int kc = 0; kc < 4; ++kc)
      Bq[qt][kc] = *(const bf8v*)&qb[(size_t)(qt * 16 + lr) * kC + kc * 32 + g * 8];

  float qmv[2];
  #pragma unroll
  for (int qt = 0; qt < 2; ++qt) qmv[qt] = qmask[b * kQ + qt * 16 + lr];

  const float c1[10] = { 129.84255368f, 100.98865286f,  72.13475204f,  43.28085123f,  14.42695041f,
                         -14.42695041f, -43.28085123f, -72.13475204f, -100.98865286f, -129.84255368f };
  const float c2[10] = { -58.42914915f, -35.34602850f, -18.03368801f, -6.49212768f, -0.72134752f,
                          -0.72134752f,  -6.49212768f, -18.03368801f, -35.34602850f, -58.42914915f };
  const float C50 = -50.f * LOG2E;
  const float C0  = -500000.f * LOG2E;

  float pk[2][kK];
  #pragma unroll
  for (int qt = 0; qt < 2; ++qt)
    #pragma unroll
    for (int k = 0; k < kK; ++k) pk[qt][k] = 0.f;

  const int dt0 = w * 8;
  bf8v An[4];
  #pragma unroll
  for (int kc = 0; kc < 4; ++kc)
    An[kc] = *(const bf8v*)&db[(size_t)(dt0 * 16 + lr) * kC + kc * 32 + g * 8];

  for (int dtl = 0; dtl < 8; ++dtl) {
    const int drow0 = (dt0 + dtl) * 16;
    bf8v Ac[4];
    #pragma unroll
    for (int kc = 0; kc < 4; ++kc) Ac[kc] = An[kc];
    if (dtl < 7) {
      #pragma unroll
      for (int kc = 0; kc < 4; ++kc)
        An[kc] = *(const bf8v*)&db[(size_t)(drow0 + 16 + lr) * kC + kc * 32 + g * 8];
    }
    f4v acc0 = (f4v)0.f, acc1 = (f4v)0.f;
    #pragma unroll
    for (int kc = 0; kc < 4; ++kc) {
      acc0 = __builtin_amdgcn_mfma_f32_16x16x32_bf16(Ac[kc], Bq[0][kc], acc0, 0, 0, 0);
      acc1 = __builtin_amdgcn_mfma_f32_16x16x32_bf16(Ac[kc], Bq[1][kc], acc1, 0, 0, 0);
    }
    float4 dmv = *(const float4*)&dmask[b * kD + drow0 + g * 4];
    #pragma unroll
    for (int qt = 0; qt < 2; ++qt) {
      const f4v& a = qt ? acc1 : acc0;
      #pragma unroll
      for (int r = 0; r < 4; ++r) {
        float dm = (r == 0) ? dmv.x : (r == 1) ? dmv.y : (r == 2) ? dmv.z : dmv.w;
        float off = fmaf(dm, 1000.f, -1000.f);
        float s = a[r] * qmv[qt] * dm;
        float s2 = s * s;
        float base = fmaf(s2, C50, off);
        float dd = s - 1.f;
        pk[qt][0] += exp2f(fmaf(dd * dd, C0, off));
        #pragma unroll
        for (int k = 0; k < 10; ++k)
          pk[qt][k + 1] += exp2f(fmaf(c1[k], s, base) + c2[k]);
      }
    }
  }

  #pragma unroll
  for (int off = 16; off < 64; off <<= 1)
    #pragma unroll
    for (int qt = 0; qt < 2; ++qt)
      #pragma unroll
      for (int k = 0; k < kK; ++k)
        pk[qt][k] += __shfl_xor(pk[qt][k], off);

  if (l < 16) {
    #pragma unroll
    for (int qt = 0; qt < 2; ++qt)
      #pragma unroll
      for (int k = 0; k < kK; ++k)
        red[w][qt][lr][k] = pk[qt][k];
  }
  __syncthreads();
  for (int i = t; i < 2 * 16 * kK; i += 256) {
    int qt = i / (16 * kK);
    int rem = i - qt * 16 * kK;
    int lq = rem / kK, k = rem - lq * kK;
    float v = red[0][qt][lq][k] + red[1][qt][lq][k] + red[2][qt][lq][k] + red[3][qt][lq][k];
    int q = qt * 16 + lq;
    pkq[(((size_t)pair * kB + b) * kQ + q) * kK + k] = v * qmask[b * kQ + q];
  }
}

// ---------------- log-pool + dense layers ----------------
__global__ __launch_bounds__(128) void finalize_kernel(
    const float* __restrict__ pkq, const float* __restrict__ qmask,
    const float* __restrict__ dmask, const float* __restrict__ nsp,
    const float* __restrict__ dw, const float* __restrict__ dbp,
    const float* __restrict__ dmw, const float* __restrict__ dmbp,
    const float* __restrict__ dcw, float* __restrict__ out)
{
  const int b = blockIdx.x;
  const int t = threadIdx.x;
  __shared__ float sh[4];
  float dl = 0.f;
  for (int d = t; d < kD; d += 128) dl += dmask[b * kD + d];
  #pragma unroll
  for (int off = 1; off < 64; off <<= 1) dl += __shfl_xor(dl, off);
  if ((t & 63) == 0) sh[t >> 6] = dl;
  __syncthreads();
  const float idl = 1.f / (sh[0] + sh[1]);
  const float sc = nsp[0];
  float ps = 0.f, pm = 0.f;
  for (int i = t; i < 99; i += 128) {
    int pr = i / kK, kk = i - pr * kK;
    const float* base = pkq + ((size_t)pr * kB + b) * kQ * kK + kk;
    float ss = 0.f, sm = 0.f;
    for (int q = 0; q < kQ; ++q) {
      float v = base[q * kK];
      float qq = qmask[b * kQ + q];
      ss += __logf(fmaxf(v, 1e-10f)) * qq;
      sm += __logf(fmaxf(v * idl, 1e-10f)) * qq;
    }
    ps += dw[i] * ss;
    pm += dmw[i] * sm;
  }
  ps *= sc; pm *= sc;
  #pragma unroll
  for (int off = 1; off < 64; off <<= 1) { ps += __shfl_xor(ps, off); pm += __shfl_xor(pm, off); }
  __syncthreads();
  if ((t & 63) == 0) { sh[t >> 6] = ps; sh[2 + (t >> 6)] = pm; }
  __syncthreads();
  if (t == 0) {
    float PS = sh[0] + sh[1] + dbp[0];
    float PM = sh[2] + sh[3] + dmbp[0];
    out[b] = dcw[0] * PS + dcw[1] * PM;
  }
}

} // namespace

extern "C" void kernel_launch(void* const* d_in, const int* in_sizes, int n_in,
                              void* d_out, int out_size, void* d_ws, size_t ws_size,
                              hipStream_t stream) {
  const float* qe  = (const float*)d_in[0];
  const float* de  = (const float*)d_in[1];
  const float* qm  = (const float*)d_in[2];
  const float* dm  = (const float*)d_in[3];
  const float* w1  = (const float*)d_in[4];
  const float* b1  = (const float*)d_in[5];
  const float* w2  = (const float*)d_in[6];
  const float* b2  = (const float*)d_in[7];
  const float* w3  = (const float*)d_in[8];
  const float* b3  = (const float*)d_in[9];
  const float* ns  = (const float*)d_in[10];
  const float* dw  = (const float*)d_in[11];
  const float* db  = (const float*)d_in[12];
  const float* dmw = (const float*)d_in[13];
  const float* dmb = (const float*)d_in[14];
  const float* dcw = (const float*)d_in[15];
  float* out = (float*)d_out;

  char* wsb = (char*)d_ws;
  __bf16* wb  = (__bf16*)wsb;
  __bf16* qnb = (__bf16*)(wsb + QNB_B);
  __bf16* dnb = (__bf16*)(wsb + DNB_B);
  float*  pkq = (float*)(wsb + PKQ_B);

  prep_kernel<<<960, 256, 0, stream>>>(w1, w2, w3, wb);
  conv_fused<<<dim3(17, kB), 256, 0, stream>>>(qe, de, wb, b1, b2, b3, qnb, dnb);
  pool_mfma<<<dim3(9, kB), 256, 0, stream>>>(qnb, dnb, qm, dm, pkq);
  finalize_kernel<<<kB, 128, 0, stream>>>(pkq, qm, dm, ns, dw, db, dmw, dmb, dcw, out);
}